// Round 12
// baseline (267.901 us; speedup 1.0000x reference)
//
#include <hip/hip_runtime.h>
#include <hip/hip_bf16.h>

#define LL 1024
#define DI 1536
#define N2 3072
#define ML 2048
#define CHUNKS 64
#define CLEN 16

typedef __attribute__((ext_vector_type(8))) short short8;
typedef __attribute__((ext_vector_type(4))) float f4;
typedef __attribute__((ext_vector_type(4))) float f32x4;

__device__ __forceinline__ ushort f2bf(float f) {
  union { float f; unsigned u; } v; v.f = f;
  unsigned u = v.u;
  u += 0x7fffu + ((u >> 16) & 1u);
  return (ushort)(u >> 16);
}
__device__ __forceinline__ float bf2f(ushort u) {
  union { unsigned i; float f; } w; w.i = ((unsigned)u) << 16; return w.f;
}
__device__ __forceinline__ f4 bf2f4(ushort4 u) {
  f4 r; r.x = bf2f(u.x); r.y = bf2f(u.y); r.z = bf2f(u.z); r.w = bf2f(u.w);
  return r;
}

// async global->LDS, 16B per lane; lds dest = wave-uniform base + lane*16
__device__ __forceinline__ void gload16(const ushort* g, ushort* l) {
  __builtin_amdgcn_global_load_lds(
      (const __attribute__((address_space(1))) unsigned int*)g,
      (__attribute__((address_space(3))) unsigned int*)l, 16, 0, 0);
}

struct CvtSeg { const float* s; ushort* d; int n4; };
struct Cvt5 { CvtSeg seg[5]; };

#define CVT_BLOCKS 5232

// merged: blocks [0,5232): fp32->bf16 over 5 segments; blocks [5232,6000):
// dt_proj weights (1536,48) -> bf16 [2][1536][64] zero-padded K
__global__ void k_cvt(Cvt5 p, int total4,
                      const float* __restrict__ wf, const float* __restrict__ wb,
                      ushort* __restrict__ dtw) {
  int bid = blockIdx.x;
  if (bid < CVT_BLOCKS) {
    int i = bid * 256 + threadIdx.x;
    if (i >= total4) return;
    int off = i, sidx = 0;
    while (sidx < 4 && off >= p.seg[sidx].n4) { off -= p.seg[sidx].n4; ++sidx; }
    f4 v = *(const f4*)(p.seg[sidx].s + (size_t)off * 4);
    ushort4 o;
    o.x = f2bf(v.x); o.y = f2bf(v.y); o.z = f2bf(v.z); o.w = f2bf(v.w);
    *(ushort4*)(p.seg[sidx].d + (size_t)off * 4) = o;
  } else {
    int i = (bid - CVT_BLOCKS) * 256 + threadIdx.x;   // 2*1536*64
    int c = i & 63;
    int rr = i >> 6;
    int dir = rr / 1536;
    int r = rr - dir * 1536;
    const float* w = dir ? wb : wf;
    dtw[i] = (c < 48) ? f2bf(w[r * 48 + c]) : (ushort)0;
  }
}

// 128x128 tile bf16 MFMA GEMM, m97 structure: global_load_lds(16B) staging
// into LINEAR LDS [128][32], C[m,n] = sum_k A[m,k]*B[n,k] (both K-major).
// EPI==0: plain. EPI==1: softplus(acc + bias[col]).
// OBF: output bf16 (ushort), else fp32.
// KS>1: split-K, blockIdx.y = nt*KS + ks, K-range [ks*kLen,(ks+1)*kLen).
// NGUARD: N < 128 (x_proj, N=80) — guarded at C-write.
// AGATE: A is computed on the fly as (Yf+Yb)*silu(Z) (bf16 streams), staged
// via registers + ds_write (gate fusion for out_proj). Same-m0 blocks share
// an XCD (x is the fast grid dim) so re-staged rows hit L2.
template<int EPI, bool NGUARD, int KS, bool OBF, bool AGATE>
__global__ __launch_bounds__(256)
void k_gemm(const ushort* __restrict__ A, const ushort* __restrict__ Bm,
            void* __restrict__ Cp, int M, int N, int K,
            const float* __restrict__ bias, const float* __restrict__ bias2,
            size_t sA, size_t sB, size_t sC, size_t sKs, int kLen,
            const ushort* __restrict__ Yf, const ushort* __restrict__ Yb,
            const ushort* __restrict__ Zz) {
  const int dir = blockIdx.z;
  A += (size_t)dir * sA;
  Bm += (size_t)dir * sB;
  size_t cbase = (size_t)dir * sC;
  const float* bp = (EPI == 1) ? (dir ? bias2 : bias) : nullptr;

  int n0, kOff, kEnd;
  if (KS > 1) {
    int yb_ = blockIdx.y;
    int nt = yb_ / KS, ks = yb_ - nt * KS;
    n0 = nt * 128;
    kOff = ks * kLen;
    kEnd = kOff + kLen;
    cbase += (size_t)ks * sKs;
  } else {
    n0 = blockIdx.y * 128;
    kOff = 0;
    kEnd = K;
  }

  __shared__ ushort As[128 * 32];   // linear, row-major [128][32]
  __shared__ ushort Bs[128 * 32];
  const int tid = threadIdx.x;
  const int m0 = blockIdx.x * 128;
  const int wv = tid >> 6;
  const int lane = tid & 63;
  const int wr = (wv >> 1) * 64;
  const int wc = (wv & 1) * 64;
  const int lr = lane & 15;
  const int lk = lane >> 4;
  f32x4 acc[4][4] = {};
  for (int k0 = kOff; k0 < kEnd; k0 += 32) {
    #pragma unroll
    for (int i = 0; i < 2; ++i) {
      int e = (tid + i * 256) * 8;
      int r = e >> 5;
      int c = e & 31;
      if (AGATE) {
        size_t ro = (size_t)(m0 + r);
        short8 vf = *(const short8*)(Yf + ro * 1536 + k0 + c);
        short8 vb = *(const short8*)(Yb + ro * 1536 + k0 + c);
        short8 vz = *(const short8*)(Zz + ro * 3072 + 1536 + k0 + c);
        short8 o;
        #pragma unroll
        for (int j = 0; j < 8; ++j) {
          float a = bf2f((ushort)vf[j]) + bf2f((ushort)vb[j]);
          float zz = bf2f((ushort)vz[j]);
          float sg = zz / (1.f + __expf(-zz));
          o[j] = (short)f2bf(a * sg);
        }
        *(short8*)(&As[e]) = o;
      } else {
        gload16(A + (size_t)(m0 + r) * K + k0 + c, &As[(i * 256 + wv * 64) * 8]);
      }
      gload16(Bm + (size_t)(n0 + r) * K + k0 + c, &Bs[(i * 256 + wv * 64) * 8]);
    }
    __syncthreads();
    short8 af[4], bfr[4];
    #pragma unroll
    for (int m = 0; m < 4; ++m) af[m] = *(const short8*)(&As[(wr + m*16 + lr) * 32 + lk*8]);
    #pragma unroll
    for (int n = 0; n < 4; ++n) bfr[n] = *(const short8*)(&Bs[(wc + n*16 + lr) * 32 + lk*8]);
    #pragma unroll
    for (int m = 0; m < 4; ++m)
      #pragma unroll
      for (int n = 0; n < 4; ++n)
        acc[m][n] = __builtin_amdgcn_mfma_f32_16x16x32_bf16(af[m], bfr[n], acc[m][n], 0, 0, 0);
    __syncthreads();
  }
  #pragma unroll
  for (int m = 0; m < 4; ++m) {
    int gr = m0 + wr + m * 16 + lk * 4;
    #pragma unroll
    for (int n = 0; n < 4; ++n) {
      int gc = n0 + wc + n * 16 + lr;
      if (NGUARD && gc >= N) continue;
      #pragma unroll
      for (int r = 0; r < 4; ++r) {
        float v = acc[m][n][r];
        if (EPI == 1) {
          v += bp[gc];
          v = (v > 20.f) ? v : log1pf(__expf(v));
        }
        size_t idx = cbase + (size_t)(gr + r) * N + gc;
        if (OBF) ((ushort*)Cp)[idx] = f2bf(v);
        else     ((float*)Cp)[idx] = v;
      }
    }
  }
}

// split-K reduce for x_proj: sum 8 partials -> dtBC fp32; pack bf16 dt
__global__ void k_xred(const float* __restrict__ partial,
                       float* __restrict__ dtBC, ushort* __restrict__ dtbf) {
  int i = blockIdx.x * 256 + threadIdx.x;   // 2*2048*20 = 81920
  int dir = i / 40960;
  int rem = i - dir * 40960;
  int row = rem / 20;
  int c4 = rem - row * 20;
  f4 s = {0.f, 0.f, 0.f, 0.f};
  #pragma unroll
  for (int ks = 0; ks < 8; ++ks) {
    f4 v = *(const f4*)(partial + (((size_t)(dir * 8 + ks) * 2048 + row) * 80 + c4 * 4));
    s.x += v.x; s.y += v.y; s.z += v.z; s.w += v.w;
  }
  *(f4*)(dtBC + ((size_t)dir * 163840 + (size_t)row * 80 + c4 * 4)) = s;
  if (c4 < 16) {
    ushort4 u;
    if (c4 < 12) { u.x = f2bf(s.x); u.y = f2bf(s.y); u.z = f2bf(s.z); u.w = f2bf(s.w); }
    else { u.x = 0; u.y = 0; u.z = 0; u.w = 0; }
    *(ushort4*)(dtbf + ((size_t)dir * 131072 + (size_t)row * 64 + c4 * 4)) = u;
  }
}

// split-K reduce for out_proj: sum 4 partials -> out
__global__ void k_ored(const float* __restrict__ part, float* __restrict__ out) {
  int i = blockIdx.x * 256 + threadIdx.x;   // 2048*768/4 = 393216
  f4 s = {0.f, 0.f, 0.f, 0.f};
  #pragma unroll
  for (int ks = 0; ks < 4; ++ks) {
    f4 v = *(const f4*)(part + (size_t)ks * 1572864 + (size_t)i * 4);
    s.x += v.x; s.y += v.y; s.z += v.z; s.w += v.w;
  }
  *(f4*)(out + (size_t)i * 4) = s;
}

// causal depthwise conv(K=4) + SiLU, BOTH dirs in one pass over bf16 xz.
#define CONV_R 8
__global__ __launch_bounds__(192)
void k_conv2(const ushort* __restrict__ xz,
             const float* __restrict__ wf, const float* __restrict__ bf_,
             const float* __restrict__ wb, const float* __restrict__ bb_,
             ushort* __restrict__ xcbf) {
  int d4 = blockIdx.z * 192 + threadIdx.x;   // 0..383
  int b = blockIdx.y;
  int l0 = blockIdx.x * CONV_R;
  int d = d4 * 4;
  f4 w0[4], w1[4];
  #pragma unroll
  for (int c = 0; c < 4; ++c) {
    w0[c] = *(const f4*)(wf + (size_t)d * 4 + c * 4);
    w1[c] = *(const f4*)(wb + (size_t)d * 4 + c * 4);
  }
  f4 bias0 = *(const f4*)(bf_ + d);
  f4 bias1 = *(const f4*)(bb_ + d);
  f4 win[CONV_R + 6];
  #pragma unroll
  for (int j = 0; j < CONV_R + 6; ++j) {
    int t = l0 - 3 + j;
    if (t >= 0 && t < LL) {
      win[j] = bf2f4(*(const ushort4*)(xz + ((size_t)(b * LL + t)) * N2 + d));
    } else {
      f4 z = {0.f, 0.f, 0.f, 0.f};
      win[j] = z;
    }
  }
  #pragma unroll
  for (int i = 0; i < CONV_R; ++i) {
    int l = l0 + i;
    float a0[4], a1[4];
    #pragma unroll
    for (int c = 0; c < 4; ++c) { a0[c] = bias0[c]; a1[c] = bias1[c]; }
    #pragma unroll
    for (int k = 0; k < 4; ++k) {
      f4 xv0 = win[i + k];        // x[l-3+k]
      f4 xv1 = win[i + 3 + k];    // x[l+k]
      #pragma unroll
      for (int c = 0; c < 4; ++c) {
        a0[c] += xv0[c] * w0[c][k];
        a1[c] += xv1[c] * w1[c][3 - k];
      }
    }
    ushort4 o0, o1;
    #pragma unroll
    for (int c = 0; c < 4; ++c) {
      a0[c] = a0[c] / (1.f + __expf(-a0[c]));
      a1[c] = a1[c] / (1.f + __expf(-a1[c]));
    }
    o0.x = f2bf(a0[0]); o0.y = f2bf(a0[1]); o0.z = f2bf(a0[2]); o0.w = f2bf(a0[3]);
    o1.x = f2bf(a1[0]); o1.y = f2bf(a1[1]); o1.z = f2bf(a1[2]); o1.w = f2bf(a1[3]);
    *(ushort4*)(xcbf + ((size_t)(b * LL + l)) * DI + d) = o0;
    *(ushort4*)(xcbf + ((size_t)(ML + b * LL + (LL - 1 - l))) * DI + d) = o1;
  }
}

// ---- chunked parallel scan: 64 chunks of 16 steps, d-per-lane ----
// K1: local scan from h=0 -> chunk-final hL[16] (bf16) + S = sum(delta).
__global__ __launch_bounds__(256)
void k_scan1(const ushort* __restrict__ delta_all,
             const ushort* __restrict__ xc_all,
             const float* __restrict__ dtBC_all,
             const float* __restrict__ Alog_f, const float* __restrict__ Alog_b,
             ushort* __restrict__ hL, float* __restrict__ Sv) {
  int dirb = blockIdx.z;               // 0..3
  int dir = dirb >> 1, b = dirb & 1;
  int ch = blockIdx.y;                 // 0..63
  int d = blockIdx.x * 256 + threadIdx.x;
  const float* Alog = dir ? Alog_b : Alog_f;
  float Av[16];
  #pragma unroll
  for (int n = 0; n < 16; ++n) Av[n] = -__expf(Alog[d * 16 + n]);
  int l0 = ch * CLEN;
  size_t base = ((size_t)dir * ML + (size_t)b * LL + l0) * DI + d;
  const ushort* dptr = delta_all + base;
  const ushort* xptr = xc_all + base;
  const float* bc = dtBC_all + ((size_t)dir * ML + (size_t)b * LL + l0) * 80 + 48;
  float h[16];
  #pragma unroll
  for (int n = 0; n < 16; ++n) h[n] = 0.f;
  float s = 0.f;
  ushort dln = dptr[0], xvn = xptr[0];
  #pragma unroll 4
  for (int l = 0; l < CLEN; ++l) {
    float dl = bf2f(dln);
    float xv = bf2f(xvn);
    if (l + 1 < CLEN) {
      dln = dptr[(size_t)(l + 1) * DI];
      xvn = xptr[(size_t)(l + 1) * DI];
    }
    float dbx = dl * xv;
    s += dl;
    const float* bp = bc + l * 80;
    #pragma unroll
    for (int q = 0; q < 4; ++q) {
      f4 Bv = *(const f4*)(bp + q * 4);
      #pragma unroll
      for (int j = 0; j < 4; ++j) {
        int n = q * 4 + j;
        h[n] = __expf(dl * Av[n]) * h[n] + dbx * Bv[j];
      }
    }
  }
  size_t si = (((size_t)dirb * CHUNKS + ch) * 1536 + d) * 16;
  #pragma unroll
  for (int q = 0; q < 4; ++q) {
    ushort4 hv;
    hv.x = f2bf(h[q*4]); hv.y = f2bf(h[q*4+1]);
    hv.z = f2bf(h[q*4+2]); hv.w = f2bf(h[q*4+3]);
    *(ushort4*)(hL + si + q * 4) = hv;
  }
  Sv[((size_t)dirb * CHUNKS + ch) * 1536 + d] = s;
}

// combine: per (dirb,d,n), sequential over 64 chunks; P = exp(Av*S) inline.
// bf16 hL in, bf16 hIn out; fp32 accumulation.
__global__ void k_comb(const ushort* __restrict__ hL, const float* __restrict__ Sv,
                       const float* __restrict__ Alog_f, const float* __restrict__ Alog_b,
                       ushort* __restrict__ hIn) {
  int tid = blockIdx.x * 256 + threadIdx.x;   // 4*24576 = 98304
  int dirb = tid / 24576;
  int e = tid - dirb * 24576;                 // d*16+n
  int d = e >> 4;
  const float* Alog = (dirb >> 1) ? Alog_b : Alog_f;
  float Av = -__expf(Alog[e]);
  size_t hbase = (size_t)dirb * CHUNKS * 24576 + e;
  size_t sbase = (size_t)dirb * CHUNKS * 1536 + d;
  float h = 0.f;
  #pragma unroll 8
  for (int ch = 0; ch < CHUNKS; ++ch) {
    hIn[hbase + (size_t)ch * 24576] = f2bf(h);
    float Pv = __expf(Av * Sv[sbase + (size_t)ch * 1536]);
    h = Pv * h + bf2f(hL[hbase + (size_t)ch * 24576]);
  }
}

// K2: rerun local scan seeded with h_in (bf16); fused C-contraction + D.
__global__ __launch_bounds__(256)
void k_scan2(const ushort* __restrict__ delta_all,
             const ushort* __restrict__ xc_all,
             const float* __restrict__ dtBC_all,
             const float* __restrict__ Alog_f, const float* __restrict__ Df,
             const float* __restrict__ Alog_b, const float* __restrict__ Db,
             const ushort* __restrict__ hIn,
             ushort* __restrict__ yf, ushort* __restrict__ yb) {
  int dirb = blockIdx.z;
  int dir = dirb >> 1, b = dirb & 1;
  int ch = blockIdx.y;
  int d = blockIdx.x * 256 + threadIdx.x;
  const float* Alog = dir ? Alog_b : Alog_f;
  const float* Dp = dir ? Db : Df;
  float Av[16];
  #pragma unroll
  for (int n = 0; n < 16; ++n) Av[n] = -__expf(Alog[d * 16 + n]);
  float Dvv = Dp[d];
  int l0 = ch * CLEN;
  size_t base = ((size_t)dir * ML + (size_t)b * LL + l0) * DI + d;
  const ushort* dptr = delta_all + base;
  const ushort* xptr = xc_all + base;
  const float* bc = dtBC_all + ((size_t)dir * ML + (size_t)b * LL + l0) * 80 + 48;
  ushort* yo = dir ? yb : yf;
  size_t si = (((size_t)dirb * CHUNKS + ch) * 1536 + d) * 16;
  float h[16];
  #pragma unroll
  for (int q = 0; q < 4; ++q) {
    ushort4 hv = *(const ushort4*)(hIn + si + q * 4);
    h[q*4] = bf2f(hv.x); h[q*4+1] = bf2f(hv.y);
    h[q*4+2] = bf2f(hv.z); h[q*4+3] = bf2f(hv.w);
  }
  ushort dln = dptr[0], xvn = xptr[0];
  #pragma unroll 4
  for (int l = 0; l < CLEN; ++l) {
    float dl = bf2f(dln);
    float xv = bf2f(xvn);
    if (l + 1 < CLEN) {
      dln = dptr[(size_t)(l + 1) * DI];
      xvn = xptr[(size_t)(l + 1) * DI];
    }
    float dbx = dl * xv;
    const float* bp = bc + l * 80;
    float pr0 = 0.f, pr1 = 0.f, pr2 = 0.f, pr3 = 0.f;
    #pragma unroll
    for (int q = 0; q < 4; ++q) {
      f4 Bv = *(const f4*)(bp + q * 4);
      f4 Cv = *(const f4*)(bp + 16 + q * 4);
      float pq = 0.f;
      #pragma unroll
      for (int j = 0; j < 4; ++j) {
        int n = q * 4 + j;
        h[n] = __expf(dl * Av[n]) * h[n] + dbx * Bv[j];
        pq += h[n] * Cv[j];
      }
      if (q == 0) pr0 = pq; else if (q == 1) pr1 = pq;
      else if (q == 2) pr2 = pq; else pr3 = pq;
    }
    float pr = (pr0 + pr1) + (pr2 + pr3);
    int gl = l0 + l;
    int lo = dir ? (LL - 1 - gl) : gl;
    yo[((size_t)b * LL + lo) * DI + d] = f2bf(pr + xv * Dvv);
  }
}

extern "C" void kernel_launch(void* const* d_in, const int* in_sizes, int n_in,
                              void* d_out, int out_size, void* d_ws, size_t ws_size,
                              hipStream_t stream) {
  const float* hidden      = (const float*)d_in[0];
  const float* in_proj_w   = (const float*)d_in[1];
  const float* conv_w      = (const float*)d_in[2];
  const float* conv_b      = (const float*)d_in[3];
  const float* x_proj_w    = (const float*)d_in[4];
  const float* dt_proj_w   = (const float*)d_in[5];
  const float* dt_proj_b   = (const float*)d_in[6];
  const float* A_log       = (const float*)d_in[7];
  const float* Dv          = (const float*)d_in[8];
  const float* conv_w_b    = (const float*)d_in[9];
  const float* conv_b_b    = (const float*)d_in[10];
  const float* x_proj_w_b  = (const float*)d_in[11];
  const float* dt_proj_w_b = (const float*)d_in[12];
  const float* dt_proj_b_b = (const float*)d_in[13];
  const float* A_b_log     = (const float*)d_in[14];
  const float* D_b         = (const float*)d_in[15];
  const float* out_proj_w  = (const float*)d_in[16];
  float* out = (float*)d_out;

  // ---- workspace layout (115.2 MB) ----
  // fp32 block (28049408 B):
  //   dtBC @0 (327680 fl), Sv @327680 (393216 fl),
  //   xpart @720896 (2621440 fl; live x_proj->xred)
  //   opart @720896 (6291456 fl; live out_proj->ored, xpart/Sv dead by then)
  float* wsf   = (float*)d_ws;
  float* dtBC  = wsf;
  float* Sv    = wsf + 327680;
  float* xpart = wsf + 720896;
  float* opart = wsf + 720896;
  // bf16 block at byte 28049408 (87130112 B):
  ushort* wsb      = (ushort*)((char*)d_ws + 28049408);
  ushort* hid_bf   = wsb;                  // 1572864
  ushort* win_bf   = wsb + 1572864;        // 2359296
  ushort* xw_bf    = wsb + 3932160;        // 2x122880
  ushort* dtw_bf   = wsb + 4177920;        // 196608
  ushort* wout_bf  = wsb + 4374528;        // 1179648
  ushort* xz_bf    = wsb + 5554176;        // 6291456 [2048][3072]
  ushort* xc_bf    = wsb + 11845632;       // 2x3145728
  ushort* dt_bf    = wsb + 18137088;       // 262144
  ushort* delta_bf = wsb + 18399232;       // 2x3145728
  ushort* ybf_f    = wsb + 24690688;       // 3145728
  ushort* ybf_b    = wsb + 27836416;       // 3145728
  ushort* hL_bf    = wsb + 30982144;       // 6291456 (bf16 chunk state)
  ushort* hIn_bf   = wsb + 37273600;       // 6291456 (ends 43565056)
  if (ws_size < 115179520) return;

  Cvt5 c5;
  c5.seg[0] = { hidden,      hid_bf,            1572864 / 4 };
  c5.seg[1] = { in_proj_w,   win_bf,            2359296 / 4 };
  c5.seg[2] = { x_proj_w,    xw_bf,             122880 / 4 };
  c5.seg[3] = { x_proj_w_b,  xw_bf + 122880,    122880 / 4 };
  c5.seg[4] = { out_proj_w,  wout_bf,           1179648 / 4 };
  k_cvt<<<CVT_BLOCKS + 768, 256, 0, stream>>>(c5, 1339392, dt_proj_w, dt_proj_w_b, dtw_bf);

  // xz = hidden @ in_proj_w.T  (2048 x 3072, K=768) -> bf16
  k_gemm<0, false, 1, true, false><<<dim3(16, 24), 256, 0, stream>>>(
      hid_bf, win_bf, xz_bf, 2048, 3072, 768, nullptr, nullptr,
      0, 0, 0, 0, 0, nullptr, nullptr, nullptr);

  // conv + silu, both dirs in one pass -> xc_bf
  k_conv2<<<dim3(LL / CONV_R, 2, 2), 192, 0, stream>>>(
      xz_bf, conv_w, conv_b, conv_w_b, conv_b_b, xc_bf);

  // x_proj both dirs, split-K 8x192 -> fp32 partials
  k_gemm<0, true, 8, false, false><<<dim3(16, 8, 2), 256, 0, stream>>>(
      xc_bf, xw_bf, xpart, 2048, 80, 1536, nullptr, nullptr,
      3145728, 122880, 1310720, 163840, 192, nullptr, nullptr, nullptr);
  k_xred<<<320, 256, 0, stream>>>(xpart, dtBC, dt_bf);

  // dt_proj + bias + softplus, both dirs -> bf16 delta
  k_gemm<1, false, 1, true, false><<<dim3(16, 12, 2), 256, 0, stream>>>(
      dt_bf, dtw_bf, delta_bf, 2048, 1536, 64, dt_proj_b, dt_proj_b_b,
      131072, 98304, 3145728, 0, 0, nullptr, nullptr, nullptr);

  // chunked scan (64 chunks x 16 steps, d-per-lane): K1 -> combine -> K2
  k_scan1<<<dim3(6, CHUNKS, 4), 256, 0, stream>>>(delta_bf, xc_bf, dtBC,
                                                  A_log, A_b_log, hL_bf, Sv);
  k_comb<<<384, 256, 0, stream>>>(hL_bf, Sv, A_log, A_b_log, hIn_bf);
  k_scan2<<<dim3(6, CHUNKS, 4), 256, 0, stream>>>(delta_bf, xc_bf, dtBC,
                                                  A_log, Dv, A_b_log, D_b,
                                                  hIn_bf, ybf_f, ybf_b);

  // out = ((yf+yb)*silu(z)) @ out_proj_w.T  (2048 x 768, K=1536),
  // gate fused into A-staging; split-K 4x384 -> partials
  k_gemm<0, false, 4, false, true><<<dim3(16, 24), 256, 0, stream>>>(
      nullptr, wout_bf, opart, 2048, 768, 1536, nullptr, nullptr,
      0, 0, 0, 1572864, 384, ybf_f, ybf_b, xz_bf);
  k_ored<<<1536, 256, 0, stream>>>(opart, out);
}

// Round 13
// 259.555 us; speedup vs baseline: 1.0322x; 1.0322x over previous
//
#include <hip/hip_runtime.h>
#include <hip/hip_bf16.h>

#define LL 1024
#define DI 1536
#define N2 3072
#define ML 2048
#define CHUNKS 64
#define CLEN 16

typedef __attribute__((ext_vector_type(8))) short short8;
typedef __attribute__((ext_vector_type(4))) float f4;
typedef __attribute__((ext_vector_type(4))) float f32x4;

__device__ __forceinline__ ushort f2bf(float f) {
  union { float f; unsigned u; } v; v.f = f;
  unsigned u = v.u;
  u += 0x7fffu + ((u >> 16) & 1u);
  return (ushort)(u >> 16);
}
__device__ __forceinline__ float bf2f(ushort u) {
  union { unsigned i; float f; } w; w.i = ((unsigned)u) << 16; return w.f;
}
__device__ __forceinline__ f4 bf2f4(ushort4 u) {
  f4 r; r.x = bf2f(u.x); r.y = bf2f(u.y); r.z = bf2f(u.z); r.w = bf2f(u.w);
  return r;
}

// async global->LDS, 16B per lane; lds dest = wave-uniform base + lane*16
__device__ __forceinline__ void gload16(const ushort* g, ushort* l) {
  __builtin_amdgcn_global_load_lds(
      (const __attribute__((address_space(1))) unsigned int*)g,
      (__attribute__((address_space(3))) unsigned int*)l, 16, 0, 0);
}

struct CvtSeg { const float* s; ushort* d; int n4; };
struct Cvt5 { CvtSeg seg[5]; };

#define CVT_BLOCKS 5232

// merged: blocks [0,5232): fp32->bf16 over 5 segments; blocks [5232,6000):
// dt_proj weights (1536,48) -> bf16 [2][1536][64] zero-padded K
__global__ void k_cvt(Cvt5 p, int total4,
                      const float* __restrict__ wf, const float* __restrict__ wb,
                      ushort* __restrict__ dtw) {
  int bid = blockIdx.x;
  if (bid < CVT_BLOCKS) {
    int i = bid * 256 + threadIdx.x;
    if (i >= total4) return;
    int off = i, sidx = 0;
    while (sidx < 4 && off >= p.seg[sidx].n4) { off -= p.seg[sidx].n4; ++sidx; }
    f4 v = *(const f4*)(p.seg[sidx].s + (size_t)off * 4);
    ushort4 o;
    o.x = f2bf(v.x); o.y = f2bf(v.y); o.z = f2bf(v.z); o.w = f2bf(v.w);
    *(ushort4*)(p.seg[sidx].d + (size_t)off * 4) = o;
  } else {
    int i = (bid - CVT_BLOCKS) * 256 + threadIdx.x;   // 2*1536*64
    int c = i & 63;
    int rr = i >> 6;
    int dir = rr / 1536;
    int r = rr - dir * 1536;
    const float* w = dir ? wb : wf;
    dtw[i] = (c < 48) ? f2bf(w[r * 48 + c]) : (ushort)0;
  }
}

// 128x128 tile bf16 MFMA GEMM, m97 structure: global_load_lds(16B) staging
// into LINEAR LDS [128][32], C[m,n] = sum_k A[m,k]*B[n,k] (both K-major).
// EPI==0: plain. EPI==1: softplus(acc + bias[col]).
// OBF: output bf16 (ushort), else fp32.
// KS>1: split-K, blockIdx.y = nt*KS + ks, K-range [ks*kLen,(ks+1)*kLen).
// NGUARD: N < 128 (x_proj, N=80) — guarded at C-write.
template<int EPI, bool NGUARD, int KS, bool OBF>
__global__ __launch_bounds__(256)
void k_gemm(const ushort* __restrict__ A, const ushort* __restrict__ Bm,
            void* __restrict__ Cp, int M, int N, int K,
            const float* __restrict__ bias, const float* __restrict__ bias2,
            size_t sA, size_t sB, size_t sC, size_t sKs, int kLen) {
  const int dir = blockIdx.z;
  A += (size_t)dir * sA;
  Bm += (size_t)dir * sB;
  size_t cbase = (size_t)dir * sC;
  const float* bp = (EPI == 1) ? (dir ? bias2 : bias) : nullptr;

  int n0, kOff, kEnd;
  if (KS > 1) {
    int yb_ = blockIdx.y;
    int nt = yb_ / KS, ks = yb_ - nt * KS;
    n0 = nt * 128;
    kOff = ks * kLen;
    kEnd = kOff + kLen;
    cbase += (size_t)ks * sKs;
  } else {
    n0 = blockIdx.y * 128;
    kOff = 0;
    kEnd = K;
  }

  __shared__ ushort As[128 * 32];   // linear, row-major [128][32]
  __shared__ ushort Bs[128 * 32];
  const int tid = threadIdx.x;
  const int m0 = blockIdx.x * 128;
  const int wv = tid >> 6;
  const int lane = tid & 63;
  const int wr = (wv >> 1) * 64;
  const int wc = (wv & 1) * 64;
  const int lr = lane & 15;
  const int lk = lane >> 4;
  f32x4 acc[4][4] = {};
  for (int k0 = kOff; k0 < kEnd; k0 += 32) {
    #pragma unroll
    for (int i = 0; i < 2; ++i) {
      int e = (tid + i * 256) * 8;
      int r = e >> 5;
      int c = e & 31;
      gload16(A + (size_t)(m0 + r) * K + k0 + c, &As[(i * 256 + wv * 64) * 8]);
      gload16(Bm + (size_t)(n0 + r) * K + k0 + c, &Bs[(i * 256 + wv * 64) * 8]);
    }
    __syncthreads();
    short8 af[4], bfr[4];
    #pragma unroll
    for (int m = 0; m < 4; ++m) af[m] = *(const short8*)(&As[(wr + m*16 + lr) * 32 + lk*8]);
    #pragma unroll
    for (int n = 0; n < 4; ++n) bfr[n] = *(const short8*)(&Bs[(wc + n*16 + lr) * 32 + lk*8]);
    #pragma unroll
    for (int m = 0; m < 4; ++m)
      #pragma unroll
      for (int n = 0; n < 4; ++n)
        acc[m][n] = __builtin_amdgcn_mfma_f32_16x16x32_bf16(af[m], bfr[n], acc[m][n], 0, 0, 0);
    __syncthreads();
  }
  #pragma unroll
  for (int m = 0; m < 4; ++m) {
    int gr = m0 + wr + m * 16 + lk * 4;
    #pragma unroll
    for (int n = 0; n < 4; ++n) {
      int gc = n0 + wc + n * 16 + lr;
      if (NGUARD && gc >= N) continue;
      #pragma unroll
      for (int r = 0; r < 4; ++r) {
        float v = acc[m][n][r];
        if (EPI == 1) {
          v += bp[gc];
          v = (v > 20.f) ? v : log1pf(__expf(v));
        }
        size_t idx = cbase + (size_t)(gr + r) * N + gc;
        if (OBF) ((ushort*)Cp)[idx] = f2bf(v);
        else     ((float*)Cp)[idx] = v;
      }
    }
  }
}

// split-K reduce for x_proj: sum 8 partials -> dtBC fp32; pack bf16 dt
__global__ void k_xred(const float* __restrict__ partial,
                       float* __restrict__ dtBC, ushort* __restrict__ dtbf) {
  int i = blockIdx.x * 256 + threadIdx.x;   // 2*2048*20 = 81920
  int dir = i / 40960;
  int rem = i - dir * 40960;
  int row = rem / 20;
  int c4 = rem - row * 20;
  f4 s = {0.f, 0.f, 0.f, 0.f};
  #pragma unroll
  for (int ks = 0; ks < 8; ++ks) {
    f4 v = *(const f4*)(partial + (((size_t)(dir * 8 + ks) * 2048 + row) * 80 + c4 * 4));
    s.x += v.x; s.y += v.y; s.z += v.z; s.w += v.w;
  }
  *(f4*)(dtBC + ((size_t)dir * 163840 + (size_t)row * 80 + c4 * 4)) = s;
  if (c4 < 16) {
    ushort4 u;
    if (c4 < 12) { u.x = f2bf(s.x); u.y = f2bf(s.y); u.z = f2bf(s.z); u.w = f2bf(s.w); }
    else { u.x = 0; u.y = 0; u.z = 0; u.w = 0; }
    *(ushort4*)(dtbf + ((size_t)dir * 131072 + (size_t)row * 64 + c4 * 4)) = u;
  }
}

// split-K reduce for out_proj: sum 4 partials -> out
__global__ void k_ored(const float* __restrict__ part, float* __restrict__ out) {
  int i = blockIdx.x * 256 + threadIdx.x;   // 2048*768/4 = 393216
  f4 s = {0.f, 0.f, 0.f, 0.f};
  #pragma unroll
  for (int ks = 0; ks < 4; ++ks) {
    f4 v = *(const f4*)(part + (size_t)ks * 1572864 + (size_t)i * 4);
    s.x += v.x; s.y += v.y; s.z += v.z; s.w += v.w;
  }
  *(f4*)(out + (size_t)i * 4) = s;
}

// causal depthwise conv(K=4) + SiLU, BOTH dirs in one pass over bf16 xz.
#define CONV_R 8
__global__ __launch_bounds__(192)
void k_conv2(const ushort* __restrict__ xz,
             const float* __restrict__ wf, const float* __restrict__ bf_,
             const float* __restrict__ wb, const float* __restrict__ bb_,
             ushort* __restrict__ xcbf) {
  int d4 = blockIdx.z * 192 + threadIdx.x;   // 0..383
  int b = blockIdx.y;
  int l0 = blockIdx.x * CONV_R;
  int d = d4 * 4;
  f4 w0[4], w1[4];
  #pragma unroll
  for (int c = 0; c < 4; ++c) {
    w0[c] = *(const f4*)(wf + (size_t)d * 4 + c * 4);
    w1[c] = *(const f4*)(wb + (size_t)d * 4 + c * 4);
  }
  f4 bias0 = *(const f4*)(bf_ + d);
  f4 bias1 = *(const f4*)(bb_ + d);
  f4 win[CONV_R + 6];
  #pragma unroll
  for (int j = 0; j < CONV_R + 6; ++j) {
    int t = l0 - 3 + j;
    if (t >= 0 && t < LL) {
      win[j] = bf2f4(*(const ushort4*)(xz + ((size_t)(b * LL + t)) * N2 + d));
    } else {
      f4 z = {0.f, 0.f, 0.f, 0.f};
      win[j] = z;
    }
  }
  #pragma unroll
  for (int i = 0; i < CONV_R; ++i) {
    int l = l0 + i;
    float a0[4], a1[4];
    #pragma unroll
    for (int c = 0; c < 4; ++c) { a0[c] = bias0[c]; a1[c] = bias1[c]; }
    #pragma unroll
    for (int k = 0; k < 4; ++k) {
      f4 xv0 = win[i + k];        // x[l-3+k]
      f4 xv1 = win[i + 3 + k];    // x[l+k]
      #pragma unroll
      for (int c = 0; c < 4; ++c) {
        a0[c] += xv0[c] * w0[c][k];
        a1[c] += xv1[c] * w1[c][3 - k];
      }
    }
    ushort4 o0, o1;
    #pragma unroll
    for (int c = 0; c < 4; ++c) {
      a0[c] = a0[c] / (1.f + __expf(-a0[c]));
      a1[c] = a1[c] / (1.f + __expf(-a1[c]));
    }
    o0.x = f2bf(a0[0]); o0.y = f2bf(a0[1]); o0.z = f2bf(a0[2]); o0.w = f2bf(a0[3]);
    o1.x = f2bf(a1[0]); o1.y = f2bf(a1[1]); o1.z = f2bf(a1[2]); o1.w = f2bf(a1[3]);
    *(ushort4*)(xcbf + ((size_t)(b * LL + l)) * DI + d) = o0;
    *(ushort4*)(xcbf + ((size_t)(ML + b * LL + (LL - 1 - l))) * DI + d) = o1;
  }
}

// ---- chunked parallel scan: 64 chunks of 16 steps, d-per-lane ----
// K1: local scan from h=0 -> chunk-final hL[16] (bf16) + S = sum(delta).
__global__ __launch_bounds__(256)
void k_scan1(const ushort* __restrict__ delta_all,
             const ushort* __restrict__ xc_all,
             const float* __restrict__ dtBC_all,
             const float* __restrict__ Alog_f, const float* __restrict__ Alog_b,
             ushort* __restrict__ hL, float* __restrict__ Sv) {
  int dirb = blockIdx.z;               // 0..3
  int dir = dirb >> 1, b = dirb & 1;
  int ch = blockIdx.y;                 // 0..63
  int d = blockIdx.x * 256 + threadIdx.x;
  const float* Alog = dir ? Alog_b : Alog_f;
  float Av[16];
  #pragma unroll
  for (int n = 0; n < 16; ++n) Av[n] = -__expf(Alog[d * 16 + n]);
  int l0 = ch * CLEN;
  size_t base = ((size_t)dir * ML + (size_t)b * LL + l0) * DI + d;
  const ushort* dptr = delta_all + base;
  const ushort* xptr = xc_all + base;
  const float* bc = dtBC_all + ((size_t)dir * ML + (size_t)b * LL + l0) * 80 + 48;
  float h[16];
  #pragma unroll
  for (int n = 0; n < 16; ++n) h[n] = 0.f;
  float s = 0.f;
  ushort dln = dptr[0], xvn = xptr[0];
  #pragma unroll 4
  for (int l = 0; l < CLEN; ++l) {
    float dl = bf2f(dln);
    float xv = bf2f(xvn);
    if (l + 1 < CLEN) {
      dln = dptr[(size_t)(l + 1) * DI];
      xvn = xptr[(size_t)(l + 1) * DI];
    }
    float dbx = dl * xv;
    s += dl;
    const float* bp = bc + l * 80;
    #pragma unroll
    for (int q = 0; q < 4; ++q) {
      f4 Bv = *(const f4*)(bp + q * 4);
      #pragma unroll
      for (int j = 0; j < 4; ++j) {
        int n = q * 4 + j;
        h[n] = __expf(dl * Av[n]) * h[n] + dbx * Bv[j];
      }
    }
  }
  size_t si = (((size_t)dirb * CHUNKS + ch) * 1536 + d) * 16;
  #pragma unroll
  for (int q = 0; q < 4; ++q) {
    ushort4 hv;
    hv.x = f2bf(h[q*4]); hv.y = f2bf(h[q*4+1]);
    hv.z = f2bf(h[q*4+2]); hv.w = f2bf(h[q*4+3]);
    *(ushort4*)(hL + si + q * 4) = hv;
  }
  Sv[((size_t)dirb * CHUNKS + ch) * 1536 + d] = s;
}

// combine: per (dirb,d,n), sequential over 64 chunks; P = exp(Av*S) inline.
// bf16 hL in, bf16 hIn out; fp32 accumulation.
__global__ void k_comb(const ushort* __restrict__ hL, const float* __restrict__ Sv,
                       const float* __restrict__ Alog_f, const float* __restrict__ Alog_b,
                       ushort* __restrict__ hIn) {
  int tid = blockIdx.x * 256 + threadIdx.x;   // 4*24576 = 98304
  int dirb = tid / 24576;
  int e = tid - dirb * 24576;                 // d*16+n
  int d = e >> 4;
  const float* Alog = (dirb >> 1) ? Alog_b : Alog_f;
  float Av = -__expf(Alog[e]);
  size_t hbase = (size_t)dirb * CHUNKS * 24576 + e;
  size_t sbase = (size_t)dirb * CHUNKS * 1536 + d;
  float h = 0.f;
  #pragma unroll 8
  for (int ch = 0; ch < CHUNKS; ++ch) {
    hIn[hbase + (size_t)ch * 24576] = f2bf(h);
    float Pv = __expf(Av * Sv[sbase + (size_t)ch * 1536]);
    h = Pv * h + bf2f(hL[hbase + (size_t)ch * 24576]);
  }
}

// K2: rerun local scan seeded with h_in (bf16); fused C-contraction + D.
__global__ __launch_bounds__(256)
void k_scan2(const ushort* __restrict__ delta_all,
             const ushort* __restrict__ xc_all,
             const float* __restrict__ dtBC_all,
             const float* __restrict__ Alog_f, const float* __restrict__ Df,
             const float* __restrict__ Alog_b, const float* __restrict__ Db,
             const ushort* __restrict__ hIn,
             ushort* __restrict__ yf, ushort* __restrict__ yb) {
  int dirb = blockIdx.z;
  int dir = dirb >> 1, b = dirb & 1;
  int ch = blockIdx.y;
  int d = blockIdx.x * 256 + threadIdx.x;
  const float* Alog = dir ? Alog_b : Alog_f;
  const float* Dp = dir ? Db : Df;
  float Av[16];
  #pragma unroll
  for (int n = 0; n < 16; ++n) Av[n] = -__expf(Alog[d * 16 + n]);
  float Dvv = Dp[d];
  int l0 = ch * CLEN;
  size_t base = ((size_t)dir * ML + (size_t)b * LL + l0) * DI + d;
  const ushort* dptr = delta_all + base;
  const ushort* xptr = xc_all + base;
  const float* bc = dtBC_all + ((size_t)dir * ML + (size_t)b * LL + l0) * 80 + 48;
  ushort* yo = dir ? yb : yf;
  size_t si = (((size_t)dirb * CHUNKS + ch) * 1536 + d) * 16;
  float h[16];
  #pragma unroll
  for (int q = 0; q < 4; ++q) {
    ushort4 hv = *(const ushort4*)(hIn + si + q * 4);
    h[q*4] = bf2f(hv.x); h[q*4+1] = bf2f(hv.y);
    h[q*4+2] = bf2f(hv.z); h[q*4+3] = bf2f(hv.w);
  }
  ushort dln = dptr[0], xvn = xptr[0];
  #pragma unroll 4
  for (int l = 0; l < CLEN; ++l) {
    float dl = bf2f(dln);
    float xv = bf2f(xvn);
    if (l + 1 < CLEN) {
      dln = dptr[(size_t)(l + 1) * DI];
      xvn = xptr[(size_t)(l + 1) * DI];
    }
    float dbx = dl * xv;
    const float* bp = bc + l * 80;
    float pr0 = 0.f, pr1 = 0.f, pr2 = 0.f, pr3 = 0.f;
    #pragma unroll
    for (int q = 0; q < 4; ++q) {
      f4 Bv = *(const f4*)(bp + q * 4);
      f4 Cv = *(const f4*)(bp + 16 + q * 4);
      float pq = 0.f;
      #pragma unroll
      for (int j = 0; j < 4; ++j) {
        int n = q * 4 + j;
        h[n] = __expf(dl * Av[n]) * h[n] + dbx * Bv[j];
        pq += h[n] * Cv[j];
      }
      if (q == 0) pr0 = pq; else if (q == 1) pr1 = pq;
      else if (q == 2) pr2 = pq; else pr3 = pq;
    }
    float pr = (pr0 + pr1) + (pr2 + pr3);
    int gl = l0 + l;
    int lo = dir ? (LL - 1 - gl) : gl;
    yo[((size_t)b * LL + lo) * DI + d] = f2bf(pr + xv * Dvv);
  }
}

// y_bf = bf16((yf + yb) * silu(z)), all bf16 in, vec4 over [2048][1536]
__global__ void k_gate(const ushort* __restrict__ a, const ushort* __restrict__ b,
                       const ushort* __restrict__ xz, ushort* __restrict__ o) {
  int i = blockIdx.x * 256 + threadIdx.x;   // 786432 groups of 4
  int row = i / 384;
  int c4 = i - row * 384;
  f4 va = bf2f4(*(const ushort4*)(a + (size_t)i * 4));
  f4 vb = bf2f4(*(const ushort4*)(b + (size_t)i * 4));
  f4 vz = bf2f4(*(const ushort4*)(xz + (size_t)row * N2 + DI + c4 * 4));
  ushort4 u;
  float s0 = vz.x / (1.f + __expf(-vz.x));
  float s1 = vz.y / (1.f + __expf(-vz.y));
  float s2 = vz.z / (1.f + __expf(-vz.z));
  float s3 = vz.w / (1.f + __expf(-vz.w));
  u.x = f2bf((va.x + vb.x) * s0);
  u.y = f2bf((va.y + vb.y) * s1);
  u.z = f2bf((va.z + vb.z) * s2);
  u.w = f2bf((va.w + vb.w) * s3);
  *(ushort4*)(o + (size_t)i * 4) = u;
}

extern "C" void kernel_launch(void* const* d_in, const int* in_sizes, int n_in,
                              void* d_out, int out_size, void* d_ws, size_t ws_size,
                              hipStream_t stream) {
  const float* hidden      = (const float*)d_in[0];
  const float* in_proj_w   = (const float*)d_in[1];
  const float* conv_w      = (const float*)d_in[2];
  const float* conv_b      = (const float*)d_in[3];
  const float* x_proj_w    = (const float*)d_in[4];
  const float* dt_proj_w   = (const float*)d_in[5];
  const float* dt_proj_b   = (const float*)d_in[6];
  const float* A_log       = (const float*)d_in[7];
  const float* Dv          = (const float*)d_in[8];
  const float* conv_w_b    = (const float*)d_in[9];
  const float* conv_b_b    = (const float*)d_in[10];
  const float* x_proj_w_b  = (const float*)d_in[11];
  const float* dt_proj_w_b = (const float*)d_in[12];
  const float* dt_proj_b_b = (const float*)d_in[13];
  const float* A_b_log     = (const float*)d_in[14];
  const float* D_b         = (const float*)d_in[15];
  const float* out_proj_w  = (const float*)d_in[16];
  float* out = (float*)d_out;

  // ---- workspace layout (121.5 MB; ws ~256 MB per fill counters) ----
  // fp32 block (28049408 B):
  //   dtBC @0 (327680 fl), Sv @327680 (393216 fl),
  //   xpart @720896 (2621440 fl; live x_proj->xred)
  //   opart @720896 (6291456 fl; live out_proj->ored, xpart/Sv dead by then)
  float* wsf   = (float*)d_ws;
  float* dtBC  = wsf;
  float* Sv    = wsf + 327680;
  float* xpart = wsf + 720896;
  float* opart = wsf + 720896;
  // bf16 block at byte 28049408:
  ushort* wsb      = (ushort*)((char*)d_ws + 28049408);
  ushort* hid_bf   = wsb;                  // 1572864
  ushort* win_bf   = wsb + 1572864;        // 2359296
  ushort* xw_bf    = wsb + 3932160;        // 2x122880
  ushort* dtw_bf   = wsb + 4177920;        // 196608
  ushort* wout_bf  = wsb + 4374528;        // 1179648
  ushort* xz_bf    = wsb + 5554176;        // 6291456 [2048][3072]
  ushort* xc_bf    = wsb + 11845632;       // 2x3145728
  ushort* dt_bf    = wsb + 18137088;       // 262144
  ushort* delta_bf = wsb + 18399232;       // 2x3145728
  ushort* ybf_f    = wsb + 24690688;       // 3145728
  ushort* ybf_b    = wsb + 27836416;       // 3145728
  ushort* hL_bf    = wsb + 30982144;       // 6291456 (bf16 chunk state)
  ushort* hIn_bf   = wsb + 37273600;       // 6291456
  ushort* y_bf     = wsb + 43565056;       // 3145728 (ends 46710784)
  if (ws_size < 121470976) return;

  Cvt5 c5;
  c5.seg[0] = { hidden,      hid_bf,            1572864 / 4 };
  c5.seg[1] = { in_proj_w,   win_bf,            2359296 / 4 };
  c5.seg[2] = { x_proj_w,    xw_bf,             122880 / 4 };
  c5.seg[3] = { x_proj_w_b,  xw_bf + 122880,    122880 / 4 };
  c5.seg[4] = { out_proj_w,  wout_bf,           1179648 / 4 };
  k_cvt<<<CVT_BLOCKS + 768, 256, 0, stream>>>(c5, 1339392, dt_proj_w, dt_proj_w_b, dtw_bf);

  // xz = hidden @ in_proj_w.T  (2048 x 3072, K=768) -> bf16
  k_gemm<0, false, 1, true><<<dim3(16, 24), 256, 0, stream>>>(
      hid_bf, win_bf, xz_bf, 2048, 3072, 768, nullptr, nullptr, 0, 0, 0, 0, 0);

  // conv + silu, both dirs in one pass -> xc_bf
  k_conv2<<<dim3(LL / CONV_R, 2, 2), 192, 0, stream>>>(
      xz_bf, conv_w, conv_b, conv_w_b, conv_b_b, xc_bf);

  // x_proj both dirs, split-K 8x192 -> fp32 partials
  k_gemm<0, true, 8, false><<<dim3(16, 8, 2), 256, 0, stream>>>(
      xc_bf, xw_bf, xpart, 2048, 80, 1536, nullptr, nullptr,
      3145728, 122880, 1310720, 163840, 192);
  k_xred<<<320, 256, 0, stream>>>(xpart, dtBC, dt_bf);

  // dt_proj + bias + softplus, both dirs -> bf16 delta
  k_gemm<1, false, 1, true><<<dim3(16, 12, 2), 256, 0, stream>>>(
      dt_bf, dtw_bf, delta_bf, 2048, 1536, 64, dt_proj_b, dt_proj_b_b,
      131072, 98304, 3145728, 0, 0);

  // chunked scan (64 chunks x 16 steps, d-per-lane): K1 -> combine -> K2
  k_scan1<<<dim3(6, CHUNKS, 4), 256, 0, stream>>>(delta_bf, xc_bf, dtBC,
                                                  A_log, A_b_log, hL_bf, Sv);
  k_comb<<<384, 256, 0, stream>>>(hL_bf, Sv, A_log, A_b_log, hIn_bf);
  k_scan2<<<dim3(6, CHUNKS, 4), 256, 0, stream>>>(delta_bf, xc_bf, dtBC,
                                                  A_log, Dv, A_b_log, D_b,
                                                  hIn_bf, ybf_f, ybf_b);

  // y_bf = bf16((yf + yb) * silu(z))
  k_gate<<<3072, 256, 0, stream>>>(ybf_f, ybf_b, xz_bf, y_bf);

  // out = y @ out_proj_w.T  (2048 x 768, K=1536), split-K 4x384 -> partials
  k_gemm<0, false, 4, false><<<dim3(16, 24), 256, 0, stream>>>(
      y_bf, wout_bf, opart, 2048, 768, 1536, nullptr, nullptr,
      0, 0, 0, 1572864, 384);
  k_ored<<<1536, 256, 0, stream>>>(opart, out);
}